// Round 8
// baseline (637.305 us; speedup 1.0000x reference)
//
#include <hip/hip_runtime.h>

#define N_NODES 50000
#define MPAD 50048            // 391 * 128, padded M for guard-free GEMM
#define N_EDGES 800000
#define H 256
#define K_CAT 512
#define G_BATCH 64
#define OUT_DIM 24

#define SCAN_BLK 256
#define NBLK ((N_NODES + SCAN_BLK - 1) / SCAN_BLK)   // 196

typedef __attribute__((ext_vector_type(8))) short short8;
typedef __attribute__((ext_vector_type(4))) float float4v;

__device__ __forceinline__ float bf2f(unsigned short u) {
    return __uint_as_float(((unsigned)u) << 16);
}
__device__ __forceinline__ unsigned short f2bf(float f) {
    unsigned x = __float_as_uint(f);
    unsigned r = (x + 0x7FFFu + ((x >> 16) & 1u)) >> 16;   // RTNE
    return (unsigned short)r;
}

__device__ __forceinline__ void async_copy16(void* lds, const void* g) {
    __builtin_amdgcn_global_load_lds(
        (const __attribute__((address_space(1))) unsigned int*)g,
        (__attribute__((address_space(3))) unsigned int*)lds, 16, 0, 0);
}

// permutation: h8 byte position b holds feature f(b) = (b&0xC0) | ((b&3)<<4) | ((b>>2)&15)
// inverse: feature f stored at b(f) = (f&0xC0) | ((f&15)<<2) | ((f>>4)&3)
// group bits preserved: b>>6 == f(b)>>6, so a 64-byte group = one scale group.

// ---------------- CSR build ----------------

__global__ void histo_kernel(const int* __restrict__ dst, int* __restrict__ deg,
                             int* __restrict__ epos) {
    int e = blockIdx.x * blockDim.x + threadIdx.x;
    if (e < N_EDGES) epos[e] = atomicAdd(&deg[dst[e]], 1);
}

__global__ void scan_block(const int* __restrict__ deg, int* __restrict__ rowptr,
                           int* __restrict__ blockSums) {
    __shared__ int s[SCAN_BLK];
    int idx = blockIdx.x * SCAN_BLK + threadIdx.x;
    int v = (idx < N_NODES) ? deg[idx] : 0;
    s[threadIdx.x] = v;
    __syncthreads();
    for (int off = 1; off < SCAN_BLK; off <<= 1) {
        int t = (threadIdx.x >= off) ? s[threadIdx.x - off] : 0;
        __syncthreads();
        s[threadIdx.x] += t;
        __syncthreads();
    }
    if (idx < N_NODES) rowptr[idx] = s[threadIdx.x] - v;
    if (threadIdx.x == SCAN_BLK - 1) blockSums[blockIdx.x] = s[threadIdx.x];
}

// each block redundantly scans the 196 chunk sums, adds its exclusive prefix
__global__ void scan_finish(int* __restrict__ rowptr, const int* __restrict__ blockSums) {
    __shared__ int s[SCAN_BLK];
    int t = threadIdx.x;
    int v = (t < NBLK) ? blockSums[t] : 0;
    s[t] = v;
    __syncthreads();
    for (int off = 1; off < SCAN_BLK; off <<= 1) {
        int tv = (t >= off) ? s[t - off] : 0;
        __syncthreads();
        s[t] += tv;
        __syncthreads();
    }
    int prefix = (blockIdx.x > 0) ? s[blockIdx.x - 1] : 0;
    int idx = blockIdx.x * SCAN_BLK + t;
    if (idx < N_NODES) rowptr[idx] += prefix;
    if (blockIdx.x == 0 && t == 0) rowptr[N_NODES] = s[NBLK - 1];
}

__global__ void fill_csr(const int* __restrict__ src, const int* __restrict__ dst,
                         const int* __restrict__ rowptr, const int* __restrict__ epos,
                         int* __restrict__ csr_src) {
    int e = blockIdx.x * blockDim.x + threadIdx.x;
    if (e >= N_EDGES) return;
    csr_src[rowptr[dst[e]] + epos[e]] = src[e];
}

// ---------------- weight prep: BOTH halves permuted to h8 byte order ----------------

__global__ void prep_weights(const float* __restrict__ w_rel, const float* __restrict__ w_root,
                             unsigned short* __restrict__ WcatT) {
    int idx = blockIdx.x * blockDim.x + threadIdx.x;    // 6*512*256
    if (idx >= 6 * K_CAT * H) return;
    int n = idx & (H - 1);
    int k = (idx >> 8) & (K_CAT - 1);
    int l = idx >> 17;
    float v;
    if (k < H) {
        int f = (k & 0xC0) | ((k & 3) << 4) | ((k >> 2) & 15);   // feature at slot k
        v = w_rel[(size_t)l * H * H + f * H + n];
    } else {
        int b = k - H;
        int f = (b & 0xC0) | ((b & 3) << 4) | ((b >> 2) & 15);   // root half permuted too
        v = w_root[(size_t)l * H * H + f * H + n];
    }
    WcatT[(size_t)l * H * K_CAT + (size_t)n * K_CAT + k] = f2bf(v);
}

// ---------------- layer 1 (F_IN=3 -> H): emits u8 h + scales only ----------------

__global__ void agg3(const float* __restrict__ x, const int* __restrict__ rowptr,
                     const int* __restrict__ csr_src, float* __restrict__ agg) {
    int n = blockIdx.x * blockDim.x + threadIdx.x;
    if (n >= N_NODES) return;
    int beg = rowptr[n], end = rowptr[n + 1];
    float a0 = 0.f, a1 = 0.f, a2 = 0.f;
    for (int i = beg; i < end; ++i) {
        int s = csr_src[i];
        a0 += x[s * 3 + 0];
        a1 += x[s * 3 + 1];
        a2 += x[s * 3 + 2];
    }
    agg[n * 3 + 0] = a0;
    agg[n * 3 + 1] = a1;
    agg[n * 3 + 2] = a2;
}

__global__ void layer1_kernel(const float* __restrict__ x, const float* __restrict__ agg,
                              const float* __restrict__ wr, const float* __restrict__ wro,
                              const float* __restrict__ bias,
                              unsigned char* __restrict__ h8, float* __restrict__ hscale) {
    __shared__ unsigned char tmp[H];
    int n = blockIdx.x;
    int f = threadIdx.x;
    float a0 = agg[n * 3 + 0], a1 = agg[n * 3 + 1], a2 = agg[n * 3 + 2];
    float x0 = x[n * 3 + 0], x1 = x[n * 3 + 1], x2 = x[n * 3 + 2];
    float v = bias[f];
    v += a0 * wr[0 * H + f] + a1 * wr[1 * H + f] + a2 * wr[2 * H + f];
    v += x0 * wro[0 * H + f] + x1 * wro[1 * H + f] + x2 * wro[2 * H + f];
    v = fmaxf(v, 0.f);
    // per-wave (= per 64-feature group) max
    float m = v;
#pragma unroll
    for (int off = 1; off < 64; off <<= 1) m = fmaxf(m, __shfl_xor(m, off, 64));
    float inv = m > 0.f ? 255.f / m : 0.f;
    tmp[(f & 0xC0) | ((f & 15) << 2) | ((f >> 4) & 3)] = (unsigned char)(v * inv + 0.5f);
    if ((f & 63) == 0) hscale[n * 4 + (f >> 6)] = m * (1.f / 255.f);
    __syncthreads();
    if (f < 64) *(unsigned*)(h8 + (size_t)n * H + f * 4) = *(const unsigned*)(tmp + f * 4);
}

// ---------------- gather-aggregate from u8 rows, 3-stage software pipeline ----------------
// one wave per node; output aggu8[node][256] + aggsc[node][4] (u8 + per-64-group scale,
// permuted byte order matching WcatT k<256). FETCH at its structural floor (~127MB
// compulsory per-XCD traffic at ~3.4 TB/s). Do not slice (r4: fetch DOUBLED). Do not
// deepen pipeline (r3: neutral). This round halves the WRITE (bf16 -> u8+scale).

__global__ __launch_bounds__(256) void aggH(unsigned char* __restrict__ aggu8,
                                            float* __restrict__ aggsc,
                                            const unsigned char* __restrict__ h8,
                                            const float* __restrict__ hscale,
                                            const int* __restrict__ rowptr,
                                            const int* __restrict__ csr_src) {
    int gtid = blockIdx.x * blockDim.x + threadIdx.x;
    int node = gtid >> 6;
    if (node >= N_NODES) return;
    int lane = threadIdx.x & 63;
    int sub = lane >> 4;
    int fl = lane & 15;
    int g = fl >> 2;
    int beg = rowptr[node], end = rowptr[node + 1];

    if (beg >= end) {
        if (sub == 0) {
            *(uint4*)(aggu8 + (size_t)node * H + fl * 16) = make_uint4(0, 0, 0, 0);
            if ((fl & 3) == 0) aggsc[node * 4 + g] = 0.f;
        }
        return;
    }

    float acc[16] = {};
    const unsigned char* base = h8 + fl * 16;
    int last = end - 1;

    int i0 = beg + sub;
    int i1 = beg + 4 + sub;
    int i2 = beg + 8 + sub;
    int i3 = beg + 12 + sub;
    int s0 = csr_src[i0 < end ? i0 : last];
    int s1 = csr_src[i1 < end ? i1 : last];
    int s2 = csr_src[i2 < end ? i2 : last];
    int s3 = csr_src[i3 < end ? i3 : last];
    float sc0 = (i0 < end) ? hscale[s0 * 4 + g] : 0.f;
    float sc1 = (i1 < end) ? hscale[s1 * 4 + g] : 0.f;
    uint4 q0 = *(const uint4*)(base + (size_t)s0 * H);
    uint4 q1 = *(const uint4*)(base + (size_t)s1 * H);

    for (int i = beg; i < end; i += 4) {
        int i4 = i + 16 + sub;
        int s4 = csr_src[i4 < end ? i4 : last];
        int ic = i + 8 + sub;
        float sc2 = (ic < end) ? hscale[s2 * 4 + g] : 0.f;
        uint4 q2 = *(const uint4*)(base + (size_t)s2 * H);

        float sc = sc0;
        acc[0]  = fmaf((float)(q0.x & 0xffu), sc, acc[0]);
        acc[1]  = fmaf((float)((q0.x >> 8) & 0xffu), sc, acc[1]);
        acc[2]  = fmaf((float)((q0.x >> 16) & 0xffu), sc, acc[2]);
        acc[3]  = fmaf((float)(q0.x >> 24), sc, acc[3]);
        acc[4]  = fmaf((float)(q0.y & 0xffu), sc, acc[4]);
        acc[5]  = fmaf((float)((q0.y >> 8) & 0xffu), sc, acc[5]);
        acc[6]  = fmaf((float)((q0.y >> 16) & 0xffu), sc, acc[6]);
        acc[7]  = fmaf((float)(q0.y >> 24), sc, acc[7]);
        acc[8]  = fmaf((float)(q0.z & 0xffu), sc, acc[8]);
        acc[9]  = fmaf((float)((q0.z >> 8) & 0xffu), sc, acc[9]);
        acc[10] = fmaf((float)((q0.z >> 16) & 0xffu), sc, acc[10]);
        acc[11] = fmaf((float)(q0.z >> 24), sc, acc[11]);
        acc[12] = fmaf((float)(q0.w & 0xffu), sc, acc[12]);
        acc[13] = fmaf((float)((q0.w >> 8) & 0xffu), sc, acc[13]);
        acc[14] = fmaf((float)((q0.w >> 16) & 0xffu), sc, acc[14]);
        acc[15] = fmaf((float)(q0.w >> 24), sc, acc[15]);

        q0 = q1; q1 = q2;
        sc0 = sc1; sc1 = sc2;
        s2 = s3; s3 = s4;
    }

#pragma unroll
    for (int j = 0; j < 16; j++) {
        acc[j] += __shfl_xor(acc[j], 16, 64);
        acc[j] += __shfl_xor(acc[j], 32, 64);
    }

    // all 64 lanes hold the full sums (xor-reduce is symmetric); group max across the
    // 4 fl-values of this scale group via xor1/xor2 (low 2 bits of fl, group preserved)
    float m = acc[0];
#pragma unroll
    for (int j = 1; j < 16; j++) m = fmaxf(m, acc[j]);
    m = fmaxf(m, __shfl_xor(m, 1, 64));
    m = fmaxf(m, __shfl_xor(m, 2, 64));
    float inv = m > 0.f ? 255.f / m : 0.f;

    if (sub == 0) {
        uint4 p;
        p.x = (unsigned)(acc[0] * inv + 0.5f)
            | ((unsigned)(acc[1] * inv + 0.5f) << 8)
            | ((unsigned)(acc[2] * inv + 0.5f) << 16)
            | ((unsigned)(acc[3] * inv + 0.5f) << 24);
        p.y = (unsigned)(acc[4] * inv + 0.5f)
            | ((unsigned)(acc[5] * inv + 0.5f) << 8)
            | ((unsigned)(acc[6] * inv + 0.5f) << 16)
            | ((unsigned)(acc[7] * inv + 0.5f) << 24);
        p.z = (unsigned)(acc[8] * inv + 0.5f)
            | ((unsigned)(acc[9] * inv + 0.5f) << 8)
            | ((unsigned)(acc[10] * inv + 0.5f) << 16)
            | ((unsigned)(acc[11] * inv + 0.5f) << 24);
        p.w = (unsigned)(acc[12] * inv + 0.5f)
            | ((unsigned)(acc[13] * inv + 0.5f) << 8)
            | ((unsigned)(acc[14] * inv + 0.5f) << 16)
            | ((unsigned)(acc[15] * inv + 0.5f) << 24);
        *(uint4*)(aggu8 + (size_t)node * H + fl * 16) = p;
        if ((fl & 3) == 0) aggsc[node * 4 + g] = m * (1.f / 255.f);
    }
}

// ---------------- MFMA GEMM: A-panel fully u8 (agg + root halves dequant-staged) ----
// Both A halves reg-staged from u8 + group scale, dequantized (q*s -> bf16 RTNE) and
// ds_write_b128'ed into the swizzled LDS layout (write slot bc^r <-> read slot
// (quad^sw)^r; this exact pair passed the harness in r7's root path). B stays
// async global_load_lds. Epilogue emits u8 h + scales only.

#define GBM 64
#define GBN 128
#define GBK 64

__global__ __launch_bounds__(256) void gemm_mfma(
    const unsigned char* __restrict__ aggu8, const float* __restrict__ aggsc,
    const unsigned char* __restrict__ h8in, const float* __restrict__ hscin,
    const unsigned short* __restrict__ WcatT, const float* __restrict__ bias,
    unsigned char* __restrict__ h8out, float* __restrict__ hscout) {
    __shared__ unsigned short sA[GBM][GBK];   // 8 KB
    __shared__ unsigned short sB[GBN][GBK];   // 16 KB

    const int tid = threadIdx.x;
    const int wave = tid >> 6;
    const int lane = tid & 63;
    const int quad = lane >> 4;
    const int l16 = lane & 15;
    const int wm0 = (wave & 1) * 32;
    const int wn0 = (wave >> 1) * 64;
    const int m0 = blockIdx.x * GBM;
    const int n0 = blockIdx.y * GBN;

    const int rowoff = lane >> 3;
    const int schunk = ((lane & 7) ^ rowoff) * 8;   // shorts
    const unsigned short* Bsrc[4];
#pragma unroll
    for (int j = 0; j < 4; j++) {
        int q = wave * 4 + j;
        Bsrc[j] = WcatT + (size_t)(n0 + q * 8 + rowoff) * K_CAT + schunk;
    }

    // A staging: thread covers rows r_row and r_row+8, byte-chunk r_bc*8 of each 64B K-block
    const int r_row = wave * 16 + (lane >> 3);
    const int r_bc = lane & 7;
    const unsigned char* a_ag0 = aggu8 + (size_t)(m0 + r_row) * H + r_bc * 8;
    const unsigned char* a_ag1 = a_ag0 + 8 * H;
    const float* sc_ag0 = aggsc + (size_t)(m0 + r_row) * 4;
    const float* sc_ag1 = sc_ag0 + 32;
    const unsigned char* a_rt0 = h8in + (size_t)(m0 + r_row) * H + r_bc * 8;
    const unsigned char* a_rt1 = a_rt0 + 8 * H;
    const float* sc_rt0 = hscin + (size_t)(m0 + r_row) * 4;
    const float* sc_rt1 = sc_rt0 + 32;
    const int ldsoff = wave * 2048 + (lane >> 3) * 128 + ((lane & 7) ^ (lane >> 3)) * 16;
    unsigned short* ldst0 = (unsigned short*)((char*)sA + ldsoff);
    unsigned short* ldst1 = (unsigned short*)((char*)sA + ldsoff + 1024);

    const int sw = l16 & 7;
    const int ca0 = (quad ^ sw) * 8;
    const int ca1 = ((4 + quad) ^ sw) * 8;

    float4v acc[2][4] = {};

#define COMPUTE()                                                            \
    {                                                                        \
        short8 a[2][2], b[4][2];                                             \
        _Pragma("unroll") for (int i = 0; i < 2; i++) {                      \
            const unsigned short* ra = &sA[wm0 + i * 16 + l16][0];           \
            a[i][0] = *(const short8*)(ra + ca0);                            \
            a[i][1] = *(const short8*)(ra + ca1);                            \
        }                                                                    \
        _Pragma("unroll") for (int i = 0; i < 4; i++) {                      \
            const unsigned short* rb = &sB[wn0 + i * 16 + l16][0];           \
            b[i][0] = *(const short8*)(rb + ca0);                            \
            b[i][1] = *(const short8*)(rb + ca1);                            \
        }                                                                    \
        _Pragma("unroll") for (int sub = 0; sub < 2; sub++)                  \
            _Pragma("unroll") for (int mi = 0; mi < 2; mi++)                 \
                _Pragma("unroll") for (int ni = 0; ni < 4; ni++)             \
                    acc[mi][ni] = __builtin_amdgcn_mfma_f32_16x16x32_bf16(   \
                        a[mi][sub], b[ni][sub], acc[mi][ni], 0, 0, 0);       \
    }

#pragma unroll
    for (int kb8 = 0; kb8 < 8; kb8++) {
        const int kb = kb8 & 3;
#pragma unroll
        for (int j = 0; j < 4; j++)
            async_copy16((char*)sB + (wave * 4 + j) * 1024, Bsrc[j] + kb8 * GBK);
        {
            const unsigned char* s0 = (kb8 < 4) ? a_ag0 : a_rt0;
            const unsigned char* s1 = (kb8 < 4) ? a_ag1 : a_rt1;
            const float* sp0 = (kb8 < 4) ? sc_ag0 : sc_rt0;
            const float* sp1 = (kb8 < 4) ? sc_ag1 : sc_rt1;
            uint2 q0 = *(const uint2*)(s0 + kb * GBK);
            uint2 q1 = *(const uint2*)(s1 + kb * GBK);
            float f0 = sp0[kb];
            float f1 = sp1[kb];
            uint4 p0, p1;
            p0.x = (unsigned)f2bf((float)(q0.x & 0xffu) * f0)
                 | ((unsigned)f2bf((float)((q0.x >> 8) & 0xffu) * f0) << 16);
            p0.y = (unsigned)f2bf((float)((q0.x >> 16) & 0xffu) * f0)
                 | ((unsigned)f2bf((float)(q0.x >> 24) * f0) << 16);
            p0.z = (unsigned)f2bf((float)(q0.y & 0xffu) * f0)
                 | ((unsigned)f2bf((float)((q0.y >> 8) & 0xffu) * f0) << 16);
            p0.w = (unsigned)f2bf((float)((q0.y >> 16) & 0xffu) * f0)
                 | ((unsigned)f2bf((float)(q0.y >> 24) * f0) << 16);
            p1.x = (unsigned)f2bf((float)(q1.x & 0xffu) * f1)
                 | ((unsigned)f2bf((float)((q1.x >> 8) & 0xffu) * f1) << 16);
            p1.y = (unsigned)f2bf((float)((q1.x >> 16) & 0xffu) * f1)
                 | ((unsigned)f2bf((float)(q1.x >> 24) * f1) << 16);
            p1.z = (unsigned)f2bf((float)(q1.y & 0xffu) * f1)
                 | ((unsigned)f2bf((float)((q1.y >> 8) & 0xffu) * f1) << 16);
            p1.w = (unsigned)f2bf((float)((q1.y >> 16) & 0xffu) * f1)
                 | ((unsigned)f2bf((float)(q1.y >> 24) * f1) << 16);
            *(uint4*)ldst0 = p0;
            *(uint4*)ldst1 = p1;
        }
        __syncthreads();
        COMPUTE();
        __syncthreads();
    }
#undef COMPUTE

    // epilogue: bias+relu, u8 h (permuted layout -> contiguous u32) + group scale
    const int hb = n0 + wn0 + l16 * 4;
    const int gsc = (n0 + wn0) >> 6;
    float bcol[4];
#pragma unroll
    for (int ni = 0; ni < 4; ni++) bcol[ni] = bias[n0 + wn0 + ni * 16 + l16];

#pragma unroll
    for (int mi = 0; mi < 2; mi++) {
        int rowb = m0 + wm0 + mi * 16 + quad * 4;
#pragma unroll
        for (int r = 0; r < 4; r++) {
            int row = rowb + r;
            float v0 = fmaxf(acc[mi][0][r] + bcol[0], 0.f);
            float v1 = fmaxf(acc[mi][1][r] + bcol[1], 0.f);
            float v2 = fmaxf(acc[mi][2][r] + bcol[2], 0.f);
            float v3 = fmaxf(acc[mi][3][r] + bcol[3], 0.f);
            float m = fmaxf(fmaxf(v0, v1), fmaxf(v2, v3));
            m = fmaxf(m, __shfl_xor(m, 1, 64));
            m = fmaxf(m, __shfl_xor(m, 2, 64));
            m = fmaxf(m, __shfl_xor(m, 4, 64));
            m = fmaxf(m, __shfl_xor(m, 8, 64));
            float inv = m > 0.f ? 255.f / m : 0.f;
            unsigned p = (unsigned)(v0 * inv + 0.5f)
                       | ((unsigned)(v1 * inv + 0.5f) << 8)
                       | ((unsigned)(v2 * inv + 0.5f) << 16)
                       | ((unsigned)(v3 * inv + 0.5f) << 24);
            *(unsigned*)(h8out + (size_t)row * H + hb) = p;
            if (l16 == 0) hscout[row * 4 + gsc] = m * (1.f / 255.f);
        }
    }
}

// ---------------- pooling (from u8 h + scales, permuted order) ----------------

__device__ __forceinline__ int lowerBound(const int* __restrict__ batch, int val) {
    int lo = 0, hi = N_NODES;
    while (lo < hi) {
        int mid = (lo + hi) >> 1;
        if (batch[mid] < val) lo = mid + 1; else hi = mid;
    }
    return lo;
}

__global__ void pool_partial(const unsigned char* __restrict__ h8,
                             const float* __restrict__ hscale,
                             const int* __restrict__ batch, float* __restrict__ pooled) {
    int g = blockIdx.x;
    int seg = blockIdx.y;
    int bpos = threadIdx.x;          // permuted byte position
    int grp = bpos >> 6;
    int start = lowerBound(batch, g);
    int end = lowerBound(batch, g + 1);
    int len = end - start;
    int s0 = start + (int)((long long)len * seg / 8);
    int s1 = start + (int)((long long)len * (seg + 1) / 8);
    float sum = 0.f;
    for (int n = s0; n < s1; ++n)
        sum += (float)h8[(size_t)n * H + bpos] * hscale[n * 4 + grp];
    if (s1 > s0)
        atomicAdd(&pooled[g * H + bpos], sum);
}

__global__ void head_kernel(const float* __restrict__ pooled, const int* __restrict__ batch,
                            const float* __restrict__ w_out, const float* __restrict__ b_out,
                            float* __restrict__ out) {
    int g = blockIdx.x;
    int o = threadIdx.x;
    int start = lowerBound(batch, g);
    int end = lowerBound(batch, g + 1);
    float cnt = fmaxf((float)(end - start), 1.f);
    float sum = 0.f;
    for (int bpos = 0; bpos < H; ++bpos) {
        int f = (bpos & 0xC0) | ((bpos & 3) << 4) | ((bpos >> 2) & 15);  // unpermute
        sum += pooled[g * H + bpos] * w_out[f * OUT_DIM + o];
    }
    out[g * OUT_DIM + o] = b_out[o] + sum / cnt;
}

// ---------------- launch ----------------

extern "C" void kernel_launch(void* const* d_in, const int* in_sizes, int n_in,
                              void* d_out, int out_size, void* d_ws, size_t ws_size,
                              hipStream_t stream) {
    const float* x      = (const float*)d_in[0];
    const int*   ei     = (const int*)d_in[1];
    const int*   batch  = (const int*)d_in[2];
    const float* w_rel1 = (const float*)d_in[3];
    const float* w_root1= (const float*)d_in[4];
    const float* b1     = (const float*)d_in[5];
    const float* w_rel  = (const float*)d_in[6];
    const float* w_root = (const float*)d_in[7];
    const float* b      = (const float*)d_in[8];
    const float* w_out  = (const float*)d_in[9];
    const float* b_out  = (const float*)d_in[10];
    float* out = (float*)d_out;

    const int* src = ei;
    const int* dst = ei + N_EDGES;

    unsigned char* aggu8 = (unsigned char*)d_ws;                         // MPAD*256 u8
    float* aggsc   = (float*)(aggu8 + (size_t)MPAD * H);                 // MPAD*4 f32
    unsigned short* WcatT = (unsigned short*)(aggsc + (size_t)MPAD * 4); // 6*256*512 bf16
    unsigned char* h8a = (unsigned char*)(WcatT + (size_t)6 * H * K_CAT);// MPAD*256 u8
    unsigned char* h8b = h8a + (size_t)MPAD * H;                         // MPAD*256 u8
    float* hsa     = (float*)(h8b + (size_t)MPAD * H);                   // MPAD*4 f32
    float* hsb     = hsa + (size_t)MPAD * 4;                             // MPAD*4 f32
    float* agg3buf = hsb + (size_t)MPAD * 4;                             // N*4 f32
    float* pooled  = agg3buf + (size_t)N_NODES * 4;                      // G*H f32
    int* rowptr    = (int*)(pooled + G_BATCH * H);                       // N+1
    int* degcur    = rowptr + (N_NODES + 1);                             // N
    int* blockSums = degcur + N_NODES;                                   // 256
    int* csr_src   = blockSums + SCAN_BLK;                               // E
    int* epos      = csr_src + N_EDGES;                                  // E

    // ---- build CSR ----
    hipMemsetAsync(degcur, 0, N_NODES * sizeof(int), stream);
    histo_kernel<<<(N_EDGES + 255) / 256, 256, 0, stream>>>(dst, degcur, epos);
    scan_block<<<NBLK, SCAN_BLK, 0, stream>>>(degcur, rowptr, blockSums);
    scan_finish<<<NBLK, SCAN_BLK, 0, stream>>>(rowptr, blockSums);
    fill_csr<<<(N_EDGES + 255) / 256, 256, 0, stream>>>(src, dst, rowptr, epos, csr_src);

    // ---- weights -> bf16 transposed cat (both halves permuted) ----
    prep_weights<<<(6 * K_CAT * H + 255) / 256, 256, 0, stream>>>(w_rel, w_root, WcatT);

    // ---- layer 1 (3 -> 256), fp32, emits u8 h + scales ----
    agg3<<<(N_NODES + 255) / 256, 256, 0, stream>>>(x, rowptr, csr_src, agg3buf);
    layer1_kernel<<<N_NODES, H, 0, stream>>>(x, agg3buf, w_rel1, w_root1, b1, h8a, hsa);

    // ---- layers 2..7 (256 -> 256), u8 gather + bf16 MFMA (fully u8 A-panel) ----
    unsigned char* h8c = h8a; float* hsc = hsa;
    unsigned char* h8n = h8b; float* hsn = hsb;
    for (int l = 0; l < 6; ++l) {
        aggH<<<(N_NODES * 64 + 255) / 256, 256, 0, stream>>>(aggu8, aggsc, h8c, hsc,
                                                             rowptr, csr_src);
        dim3 grid(MPAD / GBM, H / GBN);
        gemm_mfma<<<grid, 256, 0, stream>>>(aggu8, aggsc, h8c, hsc,
                                            WcatT + (size_t)l * H * K_CAT,
                                            b + (size_t)l * H, h8n, hsn);
        unsigned char* t8 = h8c; h8c = h8n; h8n = t8;
        float* tf = hsc; hsc = hsn; hsn = tf;
    }

    // ---- global mean pool (dequant u8) + head (unpermute) ----
    hipMemsetAsync(pooled, 0, G_BATCH * H * sizeof(float), stream);
    pool_partial<<<dim3(G_BATCH, 8), 256, 0, stream>>>(h8c, hsc, batch, pooled);
    head_kernel<<<G_BATCH, OUT_DIM, 0, stream>>>(pooled, batch, w_out, b_out, out);
}

// Round 9
// 629.619 us; speedup vs baseline: 1.0122x; 1.0122x over previous
//
#include <hip/hip_runtime.h>

#define N_NODES 50000
#define MPAD 50048            // 391 * 128, padded M for guard-free GEMM
#define N_EDGES 800000
#define H 256
#define K_CAT 512
#define G_BATCH 64
#define OUT_DIM 24

#define SCAN_BLK 256
#define NBLK ((N_NODES + SCAN_BLK - 1) / SCAN_BLK)   // 196

typedef __attribute__((ext_vector_type(8))) short short8;
typedef __attribute__((ext_vector_type(4))) float float4v;

__device__ __forceinline__ float bf2f(unsigned short u) {
    return __uint_as_float(((unsigned)u) << 16);
}
__device__ __forceinline__ unsigned short f2bf(float f) {
    unsigned x = __float_as_uint(f);
    unsigned r = (x + 0x7FFFu + ((x >> 16) & 1u)) >> 16;   // RTNE
    return (unsigned short)r;
}

__device__ __forceinline__ void async_copy16(void* lds, const void* g) {
    __builtin_amdgcn_global_load_lds(
        (const __attribute__((address_space(1))) unsigned int*)g,
        (__attribute__((address_space(3))) unsigned int*)lds, 16, 0, 0);
}

// permutation: h8 byte position b holds feature f(b) = (b&0xC0) | ((b&3)<<4) | ((b>>2)&15)
// inverse: feature f stored at b(f) = (f&0xC0) | ((f&15)<<2) | ((f>>4)&3)
// group bits preserved: b>>6 == f(b)>>6, so a 64-byte group = one scale group.

// ---------------- CSR build ----------------

__global__ void histo_kernel(const int* __restrict__ dst, int* __restrict__ deg,
                             int* __restrict__ epos) {
    int e = blockIdx.x * blockDim.x + threadIdx.x;
    if (e < N_EDGES) epos[e] = atomicAdd(&deg[dst[e]], 1);
}

__global__ void scan_block(const int* __restrict__ deg, int* __restrict__ rowptr,
                           int* __restrict__ blockSums) {
    __shared__ int s[SCAN_BLK];
    int idx = blockIdx.x * SCAN_BLK + threadIdx.x;
    int v = (idx < N_NODES) ? deg[idx] : 0;
    s[threadIdx.x] = v;
    __syncthreads();
    for (int off = 1; off < SCAN_BLK; off <<= 1) {
        int t = (threadIdx.x >= off) ? s[threadIdx.x - off] : 0;
        __syncthreads();
        s[threadIdx.x] += t;
        __syncthreads();
    }
    if (idx < N_NODES) rowptr[idx] = s[threadIdx.x] - v;
    if (threadIdx.x == SCAN_BLK - 1) blockSums[blockIdx.x] = s[threadIdx.x];
}

// each block redundantly scans the 196 chunk sums, adds its exclusive prefix
__global__ void scan_finish(int* __restrict__ rowptr, const int* __restrict__ blockSums) {
    __shared__ int s[SCAN_BLK];
    int t = threadIdx.x;
    int v = (t < NBLK) ? blockSums[t] : 0;
    s[t] = v;
    __syncthreads();
    for (int off = 1; off < SCAN_BLK; off <<= 1) {
        int tv = (t >= off) ? s[t - off] : 0;
        __syncthreads();
        s[t] += tv;
        __syncthreads();
    }
    int prefix = (blockIdx.x > 0) ? s[blockIdx.x - 1] : 0;
    int idx = blockIdx.x * SCAN_BLK + t;
    if (idx < N_NODES) rowptr[idx] += prefix;
    if (blockIdx.x == 0 && t == 0) rowptr[N_NODES] = s[NBLK - 1];
}

__global__ void fill_csr(const int* __restrict__ src, const int* __restrict__ dst,
                         const int* __restrict__ rowptr, const int* __restrict__ epos,
                         int* __restrict__ csr_src) {
    int e = blockIdx.x * blockDim.x + threadIdx.x;
    if (e >= N_EDGES) return;
    csr_src[rowptr[dst[e]] + epos[e]] = src[e];
}

// ---------------- weight prep: BOTH halves permuted to h8 byte order ----------------

__global__ void prep_weights(const float* __restrict__ w_rel, const float* __restrict__ w_root,
                             unsigned short* __restrict__ WcatT) {
    int idx = blockIdx.x * blockDim.x + threadIdx.x;    // 6*512*256
    if (idx >= 6 * K_CAT * H) return;
    int n = idx & (H - 1);
    int k = (idx >> 8) & (K_CAT - 1);
    int l = idx >> 17;
    float v;
    if (k < H) {
        int f = (k & 0xC0) | ((k & 3) << 4) | ((k >> 2) & 15);   // feature at slot k
        v = w_rel[(size_t)l * H * H + f * H + n];
    } else {
        int b = k - H;
        int f = (b & 0xC0) | ((b & 3) << 4) | ((b >> 2) & 15);   // root half permuted too
        v = w_root[(size_t)l * H * H + f * H + n];
    }
    WcatT[(size_t)l * H * K_CAT + (size_t)n * K_CAT + k] = f2bf(v);
}

// ---------------- layer 1 (F_IN=3 -> H): fused gather + dense, emits u8 h + scales ----

__global__ void layer1_kernel(const float* __restrict__ x, const int* __restrict__ rowptr,
                              const int* __restrict__ csr_src,
                              const float* __restrict__ wr, const float* __restrict__ wro,
                              const float* __restrict__ bias,
                              unsigned char* __restrict__ h8, float* __restrict__ hscale) {
    __shared__ unsigned char tmp[H];
    __shared__ float sagg[3];
    int n = blockIdx.x;
    int f = threadIdx.x;
    int lane = f & 63;

    // wave 0: 3-feature neighbor-sum gather, strided over edges, shfl-reduce
    if (f < 64) {
        int beg = rowptr[n], end = rowptr[n + 1];
        float a0 = 0.f, a1 = 0.f, a2 = 0.f;
        for (int i = beg + lane; i < end; i += 64) {
            int s = csr_src[i];
            a0 += x[s * 3 + 0];
            a1 += x[s * 3 + 1];
            a2 += x[s * 3 + 2];
        }
#pragma unroll
        for (int off = 1; off < 64; off <<= 1) {
            a0 += __shfl_xor(a0, off, 64);
            a1 += __shfl_xor(a1, off, 64);
            a2 += __shfl_xor(a2, off, 64);
        }
        if (lane == 0) { sagg[0] = a0; sagg[1] = a1; sagg[2] = a2; }
    }
    __syncthreads();

    float a0 = sagg[0], a1 = sagg[1], a2 = sagg[2];
    float x0 = x[n * 3 + 0], x1 = x[n * 3 + 1], x2 = x[n * 3 + 2];
    float v = bias[f];
    v += a0 * wr[0 * H + f] + a1 * wr[1 * H + f] + a2 * wr[2 * H + f];
    v += x0 * wro[0 * H + f] + x1 * wro[1 * H + f] + x2 * wro[2 * H + f];
    v = fmaxf(v, 0.f);
    // per-wave (= per 64-feature group) max
    float m = v;
#pragma unroll
    for (int off = 1; off < 64; off <<= 1) m = fmaxf(m, __shfl_xor(m, off, 64));
    float inv = m > 0.f ? 255.f / m : 0.f;
    tmp[(f & 0xC0) | ((f & 15) << 2) | ((f >> 4) & 3)] = (unsigned char)(v * inv + 0.5f);
    if ((f & 63) == 0) hscale[n * 4 + (f >> 6)] = m * (1.f / 255.f);
    __syncthreads();
    if (f < 64) *(unsigned*)(h8 + (size_t)n * H + f * 4) = *(const unsigned*)(tmp + f * 4);
}

// ---------------- gather-aggregate from u8 rows, 3-stage software pipeline ----------------
// one wave per node; output aggcat[node][256] bf16 in permuted (h8 byte) order,
// matching WcatT k<256. At its structural floor: compulsory per-XCD traffic ~127MB
// at ~3.4 TB/s -> ~43us. Do not slice (r4: fetch DOUBLED). Do not deepen pipeline (r3:
// neutral). Do not quantize the output (r8: write-side bytes are off the critical path).

__global__ __launch_bounds__(256) void aggH(unsigned short* __restrict__ aggcat,
                                            const unsigned char* __restrict__ h8,
                                            const float* __restrict__ hscale,
                                            const int* __restrict__ rowptr,
                                            const int* __restrict__ csr_src) {
    int gtid = blockIdx.x * blockDim.x + threadIdx.x;
    int node = gtid >> 6;
    if (node >= N_NODES) return;
    int lane = threadIdx.x & 63;
    int sub = lane >> 4;
    int fl = lane & 15;
    int g = fl >> 2;
    int beg = rowptr[node], end = rowptr[node + 1];

    if (beg >= end) {
        if (sub == 0) {
            uint4 z = make_uint4(0, 0, 0, 0);
            unsigned short* o = aggcat + (size_t)node * H + fl * 16;
            *(uint4*)o = z;
            *(uint4*)(o + 8) = z;
        }
        return;
    }

    float acc[16] = {};
    const unsigned char* base = h8 + fl * 16;
    int last = end - 1;

    int i0 = beg + sub;
    int i1 = beg + 4 + sub;
    int i2 = beg + 8 + sub;
    int i3 = beg + 12 + sub;
    int s0 = csr_src[i0 < end ? i0 : last];
    int s1 = csr_src[i1 < end ? i1 : last];
    int s2 = csr_src[i2 < end ? i2 : last];
    int s3 = csr_src[i3 < end ? i3 : last];
    float sc0 = (i0 < end) ? hscale[s0 * 4 + g] : 0.f;
    float sc1 = (i1 < end) ? hscale[s1 * 4 + g] : 0.f;
    uint4 q0 = *(const uint4*)(base + (size_t)s0 * H);
    uint4 q1 = *(const uint4*)(base + (size_t)s1 * H);

    for (int i = beg; i < end; i += 4) {
        int i4 = i + 16 + sub;
        int s4 = csr_src[i4 < end ? i4 : last];
        int ic = i + 8 + sub;
        float sc2 = (ic < end) ? hscale[s2 * 4 + g] : 0.f;
        uint4 q2 = *(const uint4*)(base + (size_t)s2 * H);

        float sc = sc0;
        acc[0]  = fmaf((float)(q0.x & 0xffu), sc, acc[0]);
        acc[1]  = fmaf((float)((q0.x >> 8) & 0xffu), sc, acc[1]);
        acc[2]  = fmaf((float)((q0.x >> 16) & 0xffu), sc, acc[2]);
        acc[3]  = fmaf((float)(q0.x >> 24), sc, acc[3]);
        acc[4]  = fmaf((float)(q0.y & 0xffu), sc, acc[4]);
        acc[5]  = fmaf((float)((q0.y >> 8) & 0xffu), sc, acc[5]);
        acc[6]  = fmaf((float)((q0.y >> 16) & 0xffu), sc, acc[6]);
        acc[7]  = fmaf((float)(q0.y >> 24), sc, acc[7]);
        acc[8]  = fmaf((float)(q0.z & 0xffu), sc, acc[8]);
        acc[9]  = fmaf((float)((q0.z >> 8) & 0xffu), sc, acc[9]);
        acc[10] = fmaf((float)((q0.z >> 16) & 0xffu), sc, acc[10]);
        acc[11] = fmaf((float)(q0.z >> 24), sc, acc[11]);
        acc[12] = fmaf((float)(q0.w & 0xffu), sc, acc[12]);
        acc[13] = fmaf((float)((q0.w >> 8) & 0xffu), sc, acc[13]);
        acc[14] = fmaf((float)((q0.w >> 16) & 0xffu), sc, acc[14]);
        acc[15] = fmaf((float)(q0.w >> 24), sc, acc[15]);

        q0 = q1; q1 = q2;
        sc0 = sc1; sc1 = sc2;
        s2 = s3; s3 = s4;
    }

#pragma unroll
    for (int j = 0; j < 16; j++) {
        acc[j] += __shfl_xor(acc[j], 16, 64);
        acc[j] += __shfl_xor(acc[j], 32, 64);
    }

    if (sub == 0) {
        unsigned short* o = aggcat + (size_t)node * H + fl * 16;
        uint4 p0, p1;
        p0.x = (unsigned)f2bf(acc[0])  | ((unsigned)f2bf(acc[1]) << 16);
        p0.y = (unsigned)f2bf(acc[2])  | ((unsigned)f2bf(acc[3]) << 16);
        p0.z = (unsigned)f2bf(acc[4])  | ((unsigned)f2bf(acc[5]) << 16);
        p0.w = (unsigned)f2bf(acc[6])  | ((unsigned)f2bf(acc[7]) << 16);
        p1.x = (unsigned)f2bf(acc[8])  | ((unsigned)f2bf(acc[9]) << 16);
        p1.y = (unsigned)f2bf(acc[10]) | ((unsigned)f2bf(acc[11]) << 16);
        p1.z = (unsigned)f2bf(acc[12]) | ((unsigned)f2bf(acc[13]) << 16);
        p1.w = (unsigned)f2bf(acc[14]) | ((unsigned)f2bf(acc[15]) << 16);
        *(uint4*)o = p0;
        *(uint4*)(o + 8) = p1;
    }
}

// ---------------- MFMA GEMM: agg half gload_lds, root half u8-dequant reg-staged ----
// (r7 verified config — best measured.) A-panel k<256 = aggcat bf16 (async
// global_load_lds, swizzled source); k>=256 = h8 u8 rows dequantized in-register and
// ds_write_b128'ed into the SAME swizzled LDS layout (write slot bc^r <-> read slot
// (quad^sw)^r). Epilogue emits u8 h + scales only (no bf16 h). h8/hscale
// double-buffered across layers. Do NOT dequant-stage the agg half too (r8: slower).

#define GBM 64
#define GBN 128
#define GBK 64

__global__ __launch_bounds__(256) void gemm_mfma(
    const unsigned short* __restrict__ aggcat, const unsigned char* __restrict__ h8in,
    const float* __restrict__ hscin, const unsigned short* __restrict__ WcatT,
    const float* __restrict__ bias,
    unsigned char* __restrict__ h8out, float* __restrict__ hscout) {
    __shared__ unsigned short sA[GBM][GBK];   // 8 KB
    __shared__ unsigned short sB[GBN][GBK];   // 16 KB

    const int tid = threadIdx.x;
    const int wave = tid >> 6;
    const int lane = tid & 63;
    const int quad = lane >> 4;
    const int l16 = lane & 15;
    const int wm0 = (wave & 1) * 32;
    const int wn0 = (wave >> 1) * 64;
    const int m0 = blockIdx.x * GBM;
    const int n0 = blockIdx.y * GBN;

    const int rowoff = lane >> 3;
    const int schunk = ((lane & 7) ^ rowoff) * 8;   // shorts
    const unsigned short* Aagg[2];
    const unsigned short* Bsrc[4];
#pragma unroll
    for (int j = 0; j < 2; j++) {
        int q = wave * 2 + j;
        Aagg[j] = aggcat + (size_t)(m0 + q * 8 + rowoff) * H + schunk;
    }
#pragma unroll
    for (int j = 0; j < 4; j++) {
        int q = wave * 4 + j;
        Bsrc[j] = WcatT + (size_t)(n0 + q * 8 + rowoff) * K_CAT + schunk;
    }

    // root-half staging: thread handles rows (wave*16 + lane/8) and +8, byte-chunk lane&7
    const int r_row = wave * 16 + (lane >> 3);
    const int r_bc = lane & 7;
    const unsigned char* r_src0 = h8in + (size_t)(m0 + r_row) * H + r_bc * 8;
    const unsigned char* r_src1 = r_src0 + 8 * H;
    const float* sc0p = hscin + (size_t)(m0 + r_row) * 4;
    const float* sc1p = sc0p + 32;
    const int ldsoff = wave * 2048 + (lane >> 3) * 128 + ((lane & 7) ^ (lane >> 3)) * 16;
    unsigned short* ldst0 = (unsigned short*)((char*)sA + ldsoff);
    unsigned short* ldst1 = (unsigned short*)((char*)sA + ldsoff + 1024);

    const int sw = l16 & 7;
    const int ca0 = (quad ^ sw) * 8;
    const int ca1 = ((4 + quad) ^ sw) * 8;

    float4v acc[2][4] = {};

#define COMPUTE()                                                            \
    {                                                                        \
        short8 a[2][2], b[4][2];                                             \
        _Pragma("unroll") for (int i = 0; i < 2; i++) {                      \
            const unsigned short* ra = &sA[wm0 + i * 16 + l16][0];           \
            a[i][0] = *(const short8*)(ra + ca0);                            \
            a[i][1] = *(const short8*)(ra + ca1);                            \
        }                                                                    \
        _Pragma("unroll") for (int i = 0; i < 4; i++) {                      \
            const unsigned short* rb = &sB[wn0 + i * 16 + l16][0];           \
            b[i][0] = *(const short8*)(rb + ca0);                            \
            b[i][1] = *(const short8*)(rb + ca1);                            \
        }                                                                    \
        _Pragma("unroll") for (int sub = 0; sub < 2; sub++)                  \
            _Pragma("unroll") for (int mi = 0; mi < 2; mi++)                 \
                _Pragma("unroll") for (int ni = 0; ni < 4; ni++)             \
                    acc[mi][ni] = __builtin_amdgcn_mfma_f32_16x16x32_bf16(   \
                        a[mi][sub], b[ni][sub], acc[mi][ni], 0, 0, 0);       \
    }

    // ---- k < 256: agg half (bf16, async gload_lds) ----
    for (int kk = 0; kk < 256; kk += GBK) {
#pragma unroll
        for (int j = 0; j < 2; j++)
            async_copy16((char*)sA + (wave * 2 + j) * 1024, Aagg[j] + kk);
#pragma unroll
        for (int j = 0; j < 4; j++)
            async_copy16((char*)sB + (wave * 4 + j) * 1024, Bsrc[j] + kk);
        __syncthreads();
        COMPUTE();
        __syncthreads();
    }

    // ---- k >= 256: root half (u8 dequant -> LDS) ----
#pragma unroll
    for (int kb = 0; kb < 4; kb++) {
        const int kk = 256 + kb * GBK;
#pragma unroll
        for (int j = 0; j < 4; j++)
            async_copy16((char*)sB + (wave * 4 + j) * 1024, Bsrc[j] + kk);
        {
            uint2 q0 = *(const uint2*)(r_src0 + kb * GBK);
            uint2 q1 = *(const uint2*)(r_src1 + kb * GBK);
            float s0 = sc0p[kb];
            float s1 = sc1p[kb];
            uint4 p0, p1;
            p0.x = (unsigned)f2bf((float)(q0.x & 0xffu) * s0)
                 | ((unsigned)f2bf((float)((q0.x >> 8) & 0xffu) * s0) << 16);
            p0.y = (unsigned)f2bf((float)((q0.x >> 16) & 0xffu) * s0)
                 | ((unsigned)f2bf((float)(q0.x >> 24) * s0) << 16);
            p0.z = (unsigned)f2bf((float)(q0.y & 0xffu) * s0)
                 | ((unsigned)f2bf((float)((q0.y >> 8) & 0xffu) * s0) << 16);
            p0.w = (unsigned)f2bf((float)((q0.y >> 16) & 0xffu) * s0)
                 | ((unsigned)f2bf((float)(q0.y >> 24) * s0) << 16);
            p1.x = (unsigned)f2bf((float)(q1.x & 0xffu) * s1)
                 | ((unsigned)f2bf((float)((q1.x >> 8) & 0xffu) * s1) << 16);
            p1.y = (unsigned)f2bf((float)((q1.x >> 16) & 0xffu) * s1)
                 | ((unsigned)f2bf((float)(q1.x >> 24) * s1) << 16);
            p1.z = (unsigned)f2bf((float)(q1.y & 0xffu) * s1)
                 | ((unsigned)f2bf((float)((q1.y >> 8) & 0xffu) * s1) << 16);
            p1.w = (unsigned)f2bf((float)((q1.y >> 16) & 0xffu) * s1)
                 | ((unsigned)f2bf((float)(q1.y >> 24) * s1) << 16);
            *(uint4*)ldst0 = p0;
            *(uint4*)ldst1 = p1;
        }
        __syncthreads();
        COMPUTE();
        __syncthreads();
    }
#undef COMPUTE

    // epilogue: bias+relu, u8 h (permuted layout -> contiguous u32) + group scale.
    const int hb = n0 + wn0 + l16 * 4;
    const int gsc = (n0 + wn0) >> 6;
    float bcol[4];
#pragma unroll
    for (int ni = 0; ni < 4; ni++) bcol[ni] = bias[n0 + wn0 + ni * 16 + l16];

#pragma unroll
    for (int mi = 0; mi < 2; mi++) {
        int rowb = m0 + wm0 + mi * 16 + quad * 4;
#pragma unroll
        for (int r = 0; r < 4; r++) {
            int row = rowb + r;
            float v0 = fmaxf(acc[mi][0][r] + bcol[0], 0.f);
            float v1 = fmaxf(acc[mi][1][r] + bcol[1], 0.f);
            float v2 = fmaxf(acc[mi][2][r] + bcol[2], 0.f);
            float v3 = fmaxf(acc[mi][3][r] + bcol[3], 0.f);
            float m = fmaxf(fmaxf(v0, v1), fmaxf(v2, v3));
            m = fmaxf(m, __shfl_xor(m, 1, 64));
            m = fmaxf(m, __shfl_xor(m, 2, 64));
            m = fmaxf(m, __shfl_xor(m, 4, 64));
            m = fmaxf(m, __shfl_xor(m, 8, 64));
            float inv = m > 0.f ? 255.f / m : 0.f;
            unsigned p = (unsigned)(v0 * inv + 0.5f)
                       | ((unsigned)(v1 * inv + 0.5f) << 8)
                       | ((unsigned)(v2 * inv + 0.5f) << 16)
                       | ((unsigned)(v3 * inv + 0.5f) << 24);
            *(unsigned*)(h8out + (size_t)row * H + hb) = p;
            if (l16 == 0) hscout[row * 4 + gsc] = m * (1.f / 255.f);
        }
    }
}

// ---------------- pooling (from u8 h + scales, permuted order) ----------------

__device__ __forceinline__ int lowerBound(const int* __restrict__ batch, int val) {
    int lo = 0, hi = N_NODES;
    while (lo < hi) {
        int mid = (lo + hi) >> 1;
        if (batch[mid] < val) lo = mid + 1; else hi = mid;
    }
    return lo;
}

__global__ void pool_partial(const unsigned char* __restrict__ h8,
                             const float* __restrict__ hscale,
                             const int* __restrict__ batch, float* __restrict__ pooled) {
    int g = blockIdx.x;
    int seg = blockIdx.y;
    int bpos = threadIdx.x;          // permuted byte position
    int grp = bpos >> 6;
    int start = lowerBound(batch, g);
    int end = lowerBound(batch, g + 1);
    int len = end - start;
    int s0 = start + (int)((long long)len * seg / 8);
    int s1 = start + (int)((long long)len * (seg + 1) / 8);
    float sum = 0.f;
    for (int n = s0; n < s1; ++n)
        sum += (float)h8[(size_t)n * H + bpos] * hscale[n * 4 + grp];
    if (s1 > s0)
        atomicAdd(&pooled[g * H + bpos], sum);
}

__global__ void head_kernel(const float* __restrict__ pooled, const int* __restrict__ batch,
                            const float* __restrict__ w_out, const float* __restrict__ b_out,
                            float* __restrict__ out) {
    int g = blockIdx.x;
    int o = threadIdx.x;
    int start = lowerBound(batch, g);
    int end = lowerBound(batch, g + 1);
    float cnt = fmaxf((float)(end - start), 1.f);
    float sum = 0.f;
    for (int bpos = 0; bpos < H; ++bpos) {
        int f = (bpos & 0xC0) | ((bpos & 3) << 4) | ((bpos >> 2) & 15);  // unpermute
        sum += pooled[g * H + bpos] * w_out[f * OUT_DIM + o];
    }
    out[g * OUT_DIM + o] = b_out[o] + sum / cnt;
}

// ---------------- launch ----------------

extern "C" void kernel_launch(void* const* d_in, const int* in_sizes, int n_in,
                              void* d_out, int out_size, void* d_ws, size_t ws_size,
                              hipStream_t stream) {
    const float* x      = (const float*)d_in[0];
    const int*   ei     = (const int*)d_in[1];
    const int*   batch  = (const int*)d_in[2];
    const float* w_rel1 = (const float*)d_in[3];
    const float* w_root1= (const float*)d_in[4];
    const float* b1     = (const float*)d_in[5];
    const float* w_rel  = (const float*)d_in[6];
    const float* w_root = (const float*)d_in[7];
    const float* b      = (const float*)d_in[8];
    const float* w_out  = (const float*)d_in[9];
    const float* b_out  = (const float*)d_in[10];
    float* out = (float*)d_out;

    const int* src = ei;
    const int* dst = ei + N_EDGES;

    unsigned short* aggcat = (unsigned short*)d_ws;                      // MPAD*256 bf16
    unsigned short* WcatT  = aggcat + (size_t)MPAD * H;                  // 6*256*512 bf16
    unsigned char* h8a = (unsigned char*)(WcatT + (size_t)6 * H * K_CAT);// MPAD*256 u8
    unsigned char* h8b = h8a + (size_t)MPAD * H;                         // MPAD*256 u8
    float* hsa     = (float*)(h8b + (size_t)MPAD * H);                   // MPAD*4 f32
    float* hsb     = hsa + (size_t)MPAD * 4;                             // MPAD*4 f32
    float* pooled  = hsb + (size_t)MPAD * 4;                             // G*H f32
    int* rowptr    = (int*)(pooled + G_BATCH * H);                       // N+1
    int* degcur    = rowptr + (N_NODES + 1);                             // N
    int* blockSums = degcur + N_NODES;                                   // 256
    int* csr_src   = blockSums + SCAN_BLK;                               // E
    int* epos      = csr_src + N_EDGES;                                  // E

    // ---- build CSR ----
    hipMemsetAsync(degcur, 0, N_NODES * sizeof(int), stream);
    histo_kernel<<<(N_EDGES + 255) / 256, 256, 0, stream>>>(dst, degcur, epos);
    scan_block<<<NBLK, SCAN_BLK, 0, stream>>>(degcur, rowptr, blockSums);
    scan_finish<<<NBLK, SCAN_BLK, 0, stream>>>(rowptr, blockSums);
    fill_csr<<<(N_EDGES + 255) / 256, 256, 0, stream>>>(src, dst, rowptr, epos, csr_src);

    // ---- weights -> bf16 transposed cat (both halves permuted) ----
    prep_weights<<<(6 * K_CAT * H + 255) / 256, 256, 0, stream>>>(w_rel, w_root, WcatT);

    // ---- layer 1 (3 -> 256), fused gather+dense, emits u8 h + scales ----
    layer1_kernel<<<N_NODES, H, 0, stream>>>(x, rowptr, csr_src, w_rel1, w_root1, b1,
                                             h8a, hsa);

    // ---- layers 2..7 (256 -> 256), u8 gather + bf16 MFMA (u8 root path) ----
    unsigned char* h8c = h8a; float* hsc = hsa;
    unsigned char* h8n = h8b; float* hsn = hsb;
    for (int l = 0; l < 6; ++l) {
        aggH<<<(N_NODES * 64 + 255) / 256, 256, 0, stream>>>(aggcat, h8c, hsc, rowptr, csr_src);
        dim3 grid(MPAD / GBM, H / GBN);
        gemm_mfma<<<grid, 256, 0, stream>>>(aggcat, h8c, hsc,
                                            WcatT + (size_t)l * H * K_CAT,
                                            b + (size_t)l * H, h8n, hsn);
        unsigned char* t8 = h8c; h8c = h8n; h8n = t8;
        float* tf = hsc; hsc = hsn; hsn = tf;
    }

    // ---- global mean pool (dequant u8) + head (unpermute) ----
    hipMemsetAsync(pooled, 0, G_BATCH * H * sizeof(float), stream);
    pool_partial<<<dim3(G_BATCH, 8), 256, 0, stream>>>(h8c, hsc, batch, pooled);
    head_kernel<<<G_BATCH, OUT_DIM, 0, stream>>>(pooled, batch, w_out, b_out, out);
}

// Round 10
// 609.812 us; speedup vs baseline: 1.0451x; 1.0325x over previous
//
#include <hip/hip_runtime.h>

#define N_NODES 50000
#define MPAD 50048            // 391 * 128, padded M for guard-free GEMM
#define N_EDGES 800000
#define H 256
#define K_CAT 512
#define G_BATCH 64
#define OUT_DIM 24

#define SCAN_BLK 256
#define NBLK ((N_NODES + SCAN_BLK - 1) / SCAN_BLK)   // 196

typedef __attribute__((ext_vector_type(8))) short short8;
typedef __attribute__((ext_vector_type(4))) float float4v;

__device__ __forceinline__ float bf2f(unsigned short u) {
    return __uint_as_float(((unsigned)u) << 16);
}
__device__ __forceinline__ unsigned short f2bf(float f) {
    unsigned x = __float_as_uint(f);
    unsigned r = (x + 0x7FFFu + ((x >> 16) & 1u)) >> 16;   // RTNE
    return (unsigned short)r;
}

__device__ __forceinline__ void async_copy16(void* lds, const void* g) {
    __builtin_amdgcn_global_load_lds(
        (const __attribute__((address_space(1))) unsigned int*)g,
        (__attribute__((address_space(3))) unsigned int*)lds, 16, 0, 0);
}

// permutation: h8 byte position b holds feature f(b) = (b&0xC0) | ((b&3)<<4) | ((b>>2)&15)
// inverse: feature f stored at b(f) = (f&0xC0) | ((f&15)<<2) | ((f>>4)&3)
// group bits preserved: b>>6 == f(b)>>6, so a 64-byte group = one scale group.

// ---------------- CSR build ----------------

__global__ void histo_kernel(const int* __restrict__ dst, int* __restrict__ deg,
                             int* __restrict__ epos) {
    int e = blockIdx.x * blockDim.x + threadIdx.x;
    if (e < N_EDGES) epos[e] = atomicAdd(&deg[dst[e]], 1);
}

__global__ void scan_block(const int* __restrict__ deg, int* __restrict__ rowptr,
                           int* __restrict__ blockSums) {
    __shared__ int s[SCAN_BLK];
    int idx = blockIdx.x * SCAN_BLK + threadIdx.x;
    int v = (idx < N_NODES) ? deg[idx] : 0;
    s[threadIdx.x] = v;
    __syncthreads();
    for (int off = 1; off < SCAN_BLK; off <<= 1) {
        int t = (threadIdx.x >= off) ? s[threadIdx.x - off] : 0;
        __syncthreads();
        s[threadIdx.x] += t;
        __syncthreads();
    }
    if (idx < N_NODES) rowptr[idx] = s[threadIdx.x] - v;
    if (threadIdx.x == SCAN_BLK - 1) blockSums[blockIdx.x] = s[threadIdx.x];
}

// each block redundantly scans the 196 chunk sums, adds its exclusive prefix
__global__ void scan_finish(int* __restrict__ rowptr, const int* __restrict__ blockSums) {
    __shared__ int s[SCAN_BLK];
    int t = threadIdx.x;
    int v = (t < NBLK) ? blockSums[t] : 0;
    s[t] = v;
    __syncthreads();
    for (int off = 1; off < SCAN_BLK; off <<= 1) {
        int tv = (t >= off) ? s[t - off] : 0;
        __syncthreads();
        s[t] += tv;
        __syncthreads();
    }
    int prefix = (blockIdx.x > 0) ? s[blockIdx.x - 1] : 0;
    int idx = blockIdx.x * SCAN_BLK + t;
    if (idx < N_NODES) rowptr[idx] += prefix;
    if (blockIdx.x == 0 && t == 0) rowptr[N_NODES] = s[NBLK - 1];
}

__global__ void fill_csr(const int* __restrict__ src, const int* __restrict__ dst,
                         const int* __restrict__ rowptr, const int* __restrict__ epos,
                         int* __restrict__ csr_src) {
    int e = blockIdx.x * blockDim.x + threadIdx.x;
    if (e >= N_EDGES) return;
    csr_src[rowptr[dst[e]] + epos[e]] = src[e];
}

// ---------------- weight prep: BOTH halves permuted to h8 byte order ----------------

__global__ void prep_weights(const float* __restrict__ w_rel, const float* __restrict__ w_root,
                             unsigned short* __restrict__ WcatT) {
    int idx = blockIdx.x * blockDim.x + threadIdx.x;    // 6*512*256
    if (idx >= 6 * K_CAT * H) return;
    int n = idx & (H - 1);
    int k = (idx >> 8) & (K_CAT - 1);
    int l = idx >> 17;
    float v;
    if (k < H) {
        int f = (k & 0xC0) | ((k & 3) << 4) | ((k >> 2) & 15);   // feature at slot k
        v = w_rel[(size_t)l * H * H + f * H + n];
    } else {
        int b = k - H;
        int f = (b & 0xC0) | ((b & 3) << 4) | ((b >> 2) & 15);   // root half permuted too
        v = w_root[(size_t)l * H * H + f * H + n];
    }
    WcatT[(size_t)l * H * K_CAT + (size_t)n * K_CAT + k] = f2bf(v);
}

// ---------------- layer 1 (F_IN=3 -> H): wave-per-node, barrier-free ----------------
// One wave per node (4 nodes/block, no __syncthreads). Lane computes 4 features
// (f = g*64+lane, one per scale group). Permuted-byte pack in-register: output byte j
// of lane l = q[group l>>4] of lane (j<<4)|(l&15)  [from b(f) inverse map], via 4
// ds_bpermute. Gather order and quantization formulas identical to the block version.

__global__ __launch_bounds__(256) void layer1_kernel(
    const float* __restrict__ x, const int* __restrict__ rowptr,
    const int* __restrict__ csr_src,
    const float* __restrict__ wr, const float* __restrict__ wro,
    const float* __restrict__ bias,
    unsigned char* __restrict__ h8, float* __restrict__ hscale) {
    int gtid = blockIdx.x * blockDim.x + threadIdx.x;
    int node = gtid >> 6;
    if (node >= N_NODES) return;
    int lane = threadIdx.x & 63;

    int beg = rowptr[node], end = rowptr[node + 1];
    float a0 = 0.f, a1 = 0.f, a2 = 0.f;
    for (int i = beg + lane; i < end; i += 64) {
        int s = csr_src[i];
        a0 += x[s * 3 + 0];
        a1 += x[s * 3 + 1];
        a2 += x[s * 3 + 2];
    }
#pragma unroll
    for (int off = 1; off < 64; off <<= 1) {
        a0 += __shfl_xor(a0, off, 64);
        a1 += __shfl_xor(a1, off, 64);
        a2 += __shfl_xor(a2, off, 64);
    }

    float x0 = x[node * 3 + 0], x1 = x[node * 3 + 1], x2 = x[node * 3 + 2];

    float v[4], mm[4];
#pragma unroll
    for (int g = 0; g < 4; g++) {
        int f = g * 64 + lane;
        float t = bias[f];
        t += a0 * wr[0 * H + f] + a1 * wr[1 * H + f] + a2 * wr[2 * H + f];
        t += x0 * wro[0 * H + f] + x1 * wro[1 * H + f] + x2 * wro[2 * H + f];
        t = fmaxf(t, 0.f);
        v[g] = t;
        float m = t;
#pragma unroll
        for (int off = 1; off < 64; off <<= 1) m = fmaxf(m, __shfl_xor(m, off, 64));
        mm[g] = m;
    }

    unsigned qp = 0;
#pragma unroll
    for (int g = 0; g < 4; g++) {
        float inv = mm[g] > 0.f ? 255.f / mm[g] : 0.f;
        qp |= ((unsigned)(v[g] * inv + 0.5f)) << (8 * g);
    }

    // in-register permuted pack: byte j of lane l's word = q[l>>4] of lane (j<<4)|(l&15)
    int grp = lane >> 4;
    unsigned w = 0;
#pragma unroll
    for (int j = 0; j < 4; j++) {
        int sj = (j << 4) | (lane & 15);
        unsigned r = (unsigned)__builtin_amdgcn_ds_bpermute(sj << 2, (int)qp);
        w |= ((r >> (8 * grp)) & 0xffu) << (8 * j);
    }
    *(unsigned*)(h8 + (size_t)node * H + lane * 4) = w;

    if (lane == 0) {
        float4 s4 = make_float4(mm[0] * (1.f / 255.f), mm[1] * (1.f / 255.f),
                                mm[2] * (1.f / 255.f), mm[3] * (1.f / 255.f));
        *(float4*)(&hscale[node * 4]) = s4;
    }
}

// ---------------- gather-aggregate from u8 rows, 3-stage software pipeline ----------------
// one wave per node; output aggcat[node][256] bf16 in permuted (h8 byte) order,
// matching WcatT k<256. At its structural floor: compulsory per-XCD traffic ~127MB
// at ~3.4 TB/s -> ~43us. Do not slice (r4: fetch DOUBLED). Do not deepen pipeline (r3:
// neutral). Do not quantize the output (r8: write-side bytes are off the critical path).

__global__ __launch_bounds__(256) void aggH(unsigned short* __restrict__ aggcat,
                                            const unsigned char* __restrict__ h8,
                                            const float* __restrict__ hscale,
                                            const int* __restrict__ rowptr,
                                            const int* __restrict__ csr_src) {
    int gtid = blockIdx.x * blockDim.x + threadIdx.x;
    int node = gtid >> 6;
    if (node >= N_NODES) return;
    int lane = threadIdx.x & 63;
    int sub = lane >> 4;
    int fl = lane & 15;
    int g = fl >> 2;
    int beg = rowptr[node], end = rowptr[node + 1];

    if (beg >= end) {
        if (sub == 0) {
            uint4 z = make_uint4(0, 0, 0, 0);
            unsigned short* o = aggcat + (size_t)node * H + fl * 16;
            *(uint4*)o = z;
            *(uint4*)(o + 8) = z;
        }
        return;
    }

    float acc[16] = {};
    const unsigned char* base = h8 + fl * 16;
    int last = end - 1;

    int i0 = beg + sub;
    int i1 = beg + 4 + sub;
    int i2 = beg + 8 + sub;
    int i3 = beg + 12 + sub;
    int s0 = csr_src[i0 < end ? i0 : last];
    int s1 = csr_src[i1 < end ? i1 : last];
    int s2 = csr_src[i2 < end ? i2 : last];
    int s3 = csr_src[i3 < end ? i3 : last];
    float sc0 = (i0 < end) ? hscale[s0 * 4 + g] : 0.f;
    float sc1 = (i1 < end) ? hscale[s1 * 4 + g] : 0.f;
    uint4 q0 = *(const uint4*)(base + (size_t)s0 * H);
    uint4 q1 = *(const uint4*)(base + (size_t)s1 * H);

    for (int i = beg; i < end; i += 4) {
        int i4 = i + 16 + sub;
        int s4 = csr_src[i4 < end ? i4 : last];
        int ic = i + 8 + sub;
        float sc2 = (ic < end) ? hscale[s2 * 4 + g] : 0.f;
        uint4 q2 = *(const uint4*)(base + (size_t)s2 * H);

        float sc = sc0;
        acc[0]  = fmaf((float)(q0.x & 0xffu), sc, acc[0]);
        acc[1]  = fmaf((float)((q0.x >> 8) & 0xffu), sc, acc[1]);
        acc[2]  = fmaf((float)((q0.x >> 16) & 0xffu), sc, acc[2]);
        acc[3]  = fmaf((float)(q0.x >> 24), sc, acc[3]);
        acc[4]  = fmaf((float)(q0.y & 0xffu), sc, acc[4]);
        acc[5]  = fmaf((float)((q0.y >> 8) & 0xffu), sc, acc[5]);
        acc[6]  = fmaf((float)((q0.y >> 16) & 0xffu), sc, acc[6]);
        acc[7]  = fmaf((float)(q0.y >> 24), sc, acc[7]);
        acc[8]  = fmaf((float)(q0.z & 0xffu), sc, acc[8]);
        acc[9]  = fmaf((float)((q0.z >> 8) & 0xffu), sc, acc[9]);
        acc[10] = fmaf((float)((q0.z >> 16) & 0xffu), sc, acc[10]);
        acc[11] = fmaf((float)(q0.z >> 24), sc, acc[11]);
        acc[12] = fmaf((float)(q0.w & 0xffu), sc, acc[12]);
        acc[13] = fmaf((float)((q0.w >> 8) & 0xffu), sc, acc[13]);
        acc[14] = fmaf((float)((q0.w >> 16) & 0xffu), sc, acc[14]);
        acc[15] = fmaf((float)(q0.w >> 24), sc, acc[15]);

        q0 = q1; q1 = q2;
        sc0 = sc1; sc1 = sc2;
        s2 = s3; s3 = s4;
    }

#pragma unroll
    for (int j = 0; j < 16; j++) {
        acc[j] += __shfl_xor(acc[j], 16, 64);
        acc[j] += __shfl_xor(acc[j], 32, 64);
    }

    if (sub == 0) {
        unsigned short* o = aggcat + (size_t)node * H + fl * 16;
        uint4 p0, p1;
        p0.x = (unsigned)f2bf(acc[0])  | ((unsigned)f2bf(acc[1]) << 16);
        p0.y = (unsigned)f2bf(acc[2])  | ((unsigned)f2bf(acc[3]) << 16);
        p0.z = (unsigned)f2bf(acc[4])  | ((unsigned)f2bf(acc[5]) << 16);
        p0.w = (unsigned)f2bf(acc[6])  | ((unsigned)f2bf(acc[7]) << 16);
        p1.x = (unsigned)f2bf(acc[8])  | ((unsigned)f2bf(acc[9]) << 16);
        p1.y = (unsigned)f2bf(acc[10]) | ((unsigned)f2bf(acc[11]) << 16);
        p1.z = (unsigned)f2bf(acc[12]) | ((unsigned)f2bf(acc[13]) << 16);
        p1.w = (unsigned)f2bf(acc[14]) | ((unsigned)f2bf(acc[15]) << 16);
        *(uint4*)o = p0;
        *(uint4*)(o + 8) = p1;
    }
}

// ---------------- MFMA GEMM: agg half gload_lds, root half u8-dequant reg-staged ----
// (r7 verified config — best measured.) A-panel k<256 = aggcat bf16 (async
// global_load_lds, swizzled source); k>=256 = h8 u8 rows dequantized in-register and
// ds_write_b128'ed into the SAME swizzled LDS layout (write slot bc^r <-> read slot
// (quad^sw)^r). Epilogue emits u8 h + scales only (no bf16 h). h8/hscale
// double-buffered across layers. Do NOT dequant-stage the agg half too (r8: slower).

#define GBM 64
#define GBN 128
#define GBK 64

__global__ __launch_bounds__(256) void gemm_mfma(
    const unsigned short* __restrict__ aggcat, const unsigned char* __restrict__ h8in,
    const float* __restrict__ hscin, const unsigned short* __restrict__ WcatT,
    const float* __restrict__ bias,
    unsigned char* __restrict__ h8out, float* __restrict__ hscout) {
    __shared__ unsigned short sA[GBM][GBK];   // 8 KB
    __shared__ unsigned short sB[GBN][GBK];   // 16 KB

    const int tid = threadIdx.x;
    const int wave = tid >> 6;
    const int lane = tid & 63;
    const int quad = lane >> 4;
    const int l16 = lane & 15;
    const int wm0 = (wave & 1) * 32;
    const int wn0 = (wave >> 1) * 64;
    const int m0 = blockIdx.x * GBM;
    const int n0 = blockIdx.y * GBN;

    const int rowoff = lane >> 3;
    const int schunk = ((lane & 7) ^ rowoff) * 8;   // shorts
    const unsigned short* Aagg[2];
    const unsigned short* Bsrc[4];
#pragma unroll
    for (int j = 0; j < 2; j++) {
        int q = wave * 2 + j;
        Aagg[j] = aggcat + (size_t)(m0 + q * 8 + rowoff) * H + schunk;
    }
#pragma unroll
    for (int j = 0; j < 4; j++) {
        int q = wave * 4 + j;
        Bsrc[j] = WcatT + (size_t)(n0 + q * 8 + rowoff) * K_CAT + schunk;
    }

    // root-half staging: thread handles rows (wave*16 + lane/8) and +8, byte-chunk lane&7
    const int r_row = wave * 16 + (lane >> 3);
    const int r_bc = lane & 7;
    const unsigned char* r_src0 = h8in + (size_t)(m0 + r_row) * H + r_bc * 8;
    const unsigned char* r_src1 = r_src0 + 8 * H;
    const float* sc0p = hscin + (size_t)(m0 + r_row) * 4;
    const float* sc1p = sc0p + 32;
    const int ldsoff = wave * 2048 + (lane >> 3) * 128 + ((lane & 7) ^ (lane >> 3)) * 16;
    unsigned short* ldst0 = (unsigned short*)((char*)sA + ldsoff);
    unsigned short* ldst1 = (unsigned short*)((char*)sA + ldsoff + 1024);

    const int sw = l16 & 7;
    const int ca0 = (quad ^ sw) * 8;
    const int ca1 = ((4 + quad) ^ sw) * 8;

    float4v acc[2][4] = {};

#define COMPUTE()                                                            \
    {                                                                        \
        short8 a[2][2], b[4][2];                                             \
        _Pragma("unroll") for (int i = 0; i < 2; i++) {                      \
            const unsigned short* ra = &sA[wm0 + i * 16 + l16][0];           \
            a[i][0] = *(const short8*)(ra + ca0);                            \
            a[i][1] = *(const short8*)(ra + ca1);                            \
        }                                                                    \
        _Pragma("unroll") for (int i = 0; i < 4; i++) {                      \
            const unsigned short* rb = &sB[wn0 + i * 16 + l16][0];           \
            b[i][0] = *(const short8*)(rb + ca0);                            \
            b[i][1] = *(const short8*)(rb + ca1);                            \
        }                                                                    \
        _Pragma("unroll") for (int sub = 0; sub < 2; sub++)                  \
            _Pragma("unroll") for (int mi = 0; mi < 2; mi++)                 \
                _Pragma("unroll") for (int ni = 0; ni < 4; ni++)             \
                    acc[mi][ni] = __builtin_amdgcn_mfma_f32_16x16x32_bf16(   \
                        a[mi][sub], b[ni][sub], acc[mi][ni], 0, 0, 0);       \
    }

    // ---- k < 256: agg half (bf16, async gload_lds) ----
    for (int kk = 0; kk < 256; kk += GBK) {
#pragma unroll
        for (int j = 0; j < 2; j++)
            async_copy16((char*)sA + (wave * 2 + j) * 1024, Aagg[j] + kk);
#pragma unroll
        for (int j = 0; j < 4; j++)
            async_copy16((char*)sB + (wave * 4 + j) * 1024, Bsrc[j] + kk);
        __syncthreads();
        COMPUTE();
        __syncthreads();
    }

    // ---- k >= 256: root half (u8 dequant -> LDS) ----
#pragma unroll
    for (int kb = 0; kb < 4; kb++) {
        const int kk = 256 + kb * GBK;
#pragma unroll
        for (int j = 0; j < 4; j++)
            async_copy16((char*)sB + (wave * 4 + j) * 1024, Bsrc[j] + kk);
        {
            uint2 q0 = *(const uint2*)(r_src0 + kb * GBK);
            uint2 q1 = *(const uint2*)(r_src1 + kb * GBK);
            float s0 = sc0p[kb];
            float s1 = sc1p[kb];
            uint4 p0, p1;
            p0.x = (unsigned)f2bf((float)(q0.x & 0xffu) * s0)
                 | ((unsigned)f2bf((float)((q0.x >> 8) & 0xffu) * s0) << 16);
            p0.y = (unsigned)f2bf((float)((q0.x >> 16) & 0xffu) * s0)
                 | ((unsigned)f2bf((float)(q0.x >> 24) * s0) << 16);
            p0.z = (unsigned)f2bf((float)(q0.y & 0xffu) * s0)
                 | ((unsigned)f2bf((float)((q0.y >> 8) & 0xffu) * s0) << 16);
            p0.w = (unsigned)f2bf((float)((q0.y >> 16) & 0xffu) * s0)
                 | ((unsigned)f2bf((float)(q0.y >> 24) * s0) << 16);
            p1.x = (unsigned)f2bf((float)(q1.x & 0xffu) * s1)
                 | ((unsigned)f2bf((float)((q1.x >> 8) & 0xffu) * s1) << 16);
            p1.y = (unsigned)f2bf((float)((q1.x >> 16) & 0xffu) * s1)
                 | ((unsigned)f2bf((float)(q1.x >> 24) * s1) << 16);
            p1.z = (unsigned)f2bf((float)(q1.y & 0xffu) * s1)
                 | ((unsigned)f2bf((float)((q1.y >> 8) & 0xffu) * s1) << 16);
            p1.w = (unsigned)f2bf((float)((q1.y >> 16) & 0xffu) * s1)
                 | ((unsigned)f2bf((float)(q1.y >> 24) * s1) << 16);
            *(uint4*)ldst0 = p0;
            *(uint4*)ldst1 = p1;
        }
        __syncthreads();
        COMPUTE();
        __syncthreads();
    }
#undef COMPUTE

    // epilogue: bias+relu, u8 h (permuted layout -> contiguous u32) + group scale.
    const int hb = n0 + wn0 + l16 * 4;
    const int gsc = (n0 + wn0) >> 6;
    float bcol[4];
#pragma unroll
    for (int ni = 0; ni < 4; ni++) bcol[ni] = bias[n0 + wn0 + ni * 16 + l16];

#pragma unroll
    for (int mi = 0; mi < 2; mi++) {
        int rowb = m0 + wm0 + mi * 16 + quad * 4;
#pragma unroll
        for (int r = 0; r < 4; r++) {
            int row = rowb + r;
            float v0 = fmaxf(acc[mi][0][r] + bcol[0], 0.f);
            float v1 = fmaxf(acc[mi][1][r] + bcol[1], 0.f);
            float v2 = fmaxf(acc[mi][2][r] + bcol[2], 0.f);
            float v3 = fmaxf(acc[mi][3][r] + bcol[3], 0.f);
            float m = fmaxf(fmaxf(v0, v1), fmaxf(v2, v3));
            m = fmaxf(m, __shfl_xor(m, 1, 64));
            m = fmaxf(m, __shfl_xor(m, 2, 64));
            m = fmaxf(m, __shfl_xor(m, 4, 64));
            m = fmaxf(m, __shfl_xor(m, 8, 64));
            float inv = m > 0.f ? 255.f / m : 0.f;
            unsigned p = (unsigned)(v0 * inv + 0.5f)
                       | ((unsigned)(v1 * inv + 0.5f) << 8)
                       | ((unsigned)(v2 * inv + 0.5f) << 16)
                       | ((unsigned)(v3 * inv + 0.5f) << 24);
            *(unsigned*)(h8out + (size_t)row * H + hb) = p;
            if (l16 == 0) hscout[row * 4 + gsc] = m * (1.f / 255.f);
        }
    }
}

// ---------------- pooling (from u8 h + scales, permuted order) ----------------

__device__ __forceinline__ int lowerBound(const int* __restrict__ batch, int val) {
    int lo = 0, hi = N_NODES;
    while (lo < hi) {
        int mid = (lo + hi) >> 1;
        if (batch[mid] < val) lo = mid + 1; else hi = mid;
    }
    return lo;
}

__global__ void pool_partial(const unsigned char* __restrict__ h8,
                             const float* __restrict__ hscale,
                             const int* __restrict__ batch, float* __restrict__ pooled) {
    int g = blockIdx.x;
    int seg = blockIdx.y;
    int bpos = threadIdx.x;          // permuted byte position
    int grp = bpos >> 6;
    int start = lowerBound(batch, g);
    int end = lowerBound(batch, g + 1);
    int len = end - start;
    int s0 = start + (int)((long long)len * seg / 8);
    int s1 = start + (int)((long long)len * (seg + 1) / 8);
    float sum = 0.f;
    for (int n = s0; n < s1; ++n)
        sum += (float)h8[(size_t)n * H + bpos] * hscale[n * 4 + grp];
    if (s1 > s0)
        atomicAdd(&pooled[g * H + bpos], sum);
}

__global__ void head_kernel(const float* __restrict__ pooled, const int* __restrict__ batch,
                            const float* __restrict__ w_out, const float* __restrict__ b_out,
                            float* __restrict__ out) {
    int g = blockIdx.x;
    int o = threadIdx.x;
    int start = lowerBound(batch, g);
    int end = lowerBound(batch, g + 1);
    float cnt = fmaxf((float)(end - start), 1.f);
    float sum = 0.f;
    for (int bpos = 0; bpos < H; ++bpos) {
        int f = (bpos & 0xC0) | ((bpos & 3) << 4) | ((bpos >> 2) & 15);  // unpermute
        sum += pooled[g * H + bpos] * w_out[f * OUT_DIM + o];
    }
    out[g * OUT_DIM + o] = b_out[o] + sum / cnt;
}

// ---------------- launch ----------------

extern "C" void kernel_launch(void* const* d_in, const int* in_sizes, int n_in,
                              void* d_out, int out_size, void* d_ws, size_t ws_size,
                              hipStream_t stream) {
    const float* x      = (const float*)d_in[0];
    const int*   ei     = (const int*)d_in[1];
    const int*   batch  = (const int*)d_in[2];
    const float* w_rel1 = (const float*)d_in[3];
    const float* w_root1= (const float*)d_in[4];
    const float* b1     = (const float*)d_in[5];
    const float* w_rel  = (const float*)d_in[6];
    const float* w_root = (const float*)d_in[7];
    const float* b      = (const float*)d_in[8];
    const float* w_out  = (const float*)d_in[9];
    const float* b_out  = (const float*)d_in[10];
    float* out = (float*)d_out;

    const int* src = ei;
    const int* dst = ei + N_EDGES;

    unsigned short* aggcat = (unsigned short*)d_ws;                      // MPAD*256 bf16
    unsigned short* WcatT  = aggcat + (size_t)MPAD * H;                  // 6*256*512 bf16
    unsigned char* h8a = (unsigned char*)(WcatT + (size_t)6 * H * K_CAT);// MPAD*256 u8
    unsigned char* h8b = h8a + (size_t)MPAD * H;                         // MPAD*256 u8
    float* hsa     = (float*)(h8b + (size_t)MPAD * H);                   // MPAD*4 f32
    float* hsb     = hsa + (size_t)MPAD * 4;                             // MPAD*4 f32
    float* pooled  = hsb + (size_t)MPAD * 4;                             // G*H f32
    int* rowptr    = (int*)(pooled + G_BATCH * H);                       // N+1
    int* degcur    = rowptr + (N_NODES + 1);                             // N
    int* blockSums = degcur + N_NODES;                                   // 256
    int* csr_src   = blockSums + SCAN_BLK;                               // E
    int* epos      = csr_src + N_EDGES;                                  // E

    // ---- build CSR ----
    hipMemsetAsync(degcur, 0, N_NODES * sizeof(int), stream);
    histo_kernel<<<(N_EDGES + 255) / 256, 256, 0, stream>>>(dst, degcur, epos);
    scan_block<<<NBLK, SCAN_BLK, 0, stream>>>(degcur, rowptr, blockSums);
    scan_finish<<<NBLK, SCAN_BLK, 0, stream>>>(rowptr, blockSums);
    fill_csr<<<(N_EDGES + 255) / 256, 256, 0, stream>>>(src, dst, rowptr, epos, csr_src);

    // ---- weights -> bf16 transposed cat (both halves permuted) ----
    prep_weights<<<(6 * K_CAT * H + 255) / 256, 256, 0, stream>>>(w_rel, w_root, WcatT);

    // ---- layer 1 (3 -> 256), wave-per-node fused gather+dense, emits u8 h + scales ----
    layer1_kernel<<<(N_NODES * 64 + 255) / 256, 256, 0, stream>>>(
        x, rowptr, csr_src, w_rel1, w_root1, b1, h8a, hsa);

    // ---- layers 2..7 (256 -> 256), u8 gather + bf16 MFMA (u8 root path) ----
    unsigned char* h8c = h8a; float* hsc = hsa;
    unsigned char* h8n = h8b; float* hsn = hsb;
    for (int l = 0; l < 6; ++l) {
        aggH<<<(N_NODES * 64 + 255) / 256, 256, 0, stream>>>(aggcat, h8c, hsc, rowptr, csr_src);
        dim3 grid(MPAD / GBM, H / GBN);
        gemm_mfma<<<grid, 256, 0, stream>>>(aggcat, h8c, hsc,
                                            WcatT + (size_t)l * H * K_CAT,
                                            b + (size_t)l * H, h8n, hsn);
        unsigned char* t8 = h8c; h8c = h8n; h8n = t8;
        float* tf = hsc; hsc = hsn; hsn = tf;
    }

    // ---- global mean pool (dequant u8) + head (unpermute) ----
    hipMemsetAsync(pooled, 0, G_BATCH * H * sizeof(float), stream);
    pool_partial<<<dim3(G_BATCH, 8), 256, 0, stream>>>(h8c, hsc, batch, pooled);
    head_kernel<<<G_BATCH, OUT_DIM, 0, stream>>>(pooled, batch, w_out, b_out, out);
}